// Round 11
// baseline (189.865 us; speedup 1.0000x reference)
//
#include <hip/hip_runtime.h>
#include <math.h>

// ---------------------------------------------------------------------------
// NB regression log-posterior, two-pass. (R8 structure, launch_bounds(256,5)
// so all 5 blocks/CU are co-resident: single-round schedule, no 256-block
// tail. R10 showed occupancy ~26% / two-round schedule was the remaining
// slack: VALU total ~21us + BW floor ~13us vs measured 45-48us per pass.)
//   setup:  priors + per-gene r, cg = r*log r - lgamma(r)
//   pre:    sy[n] = sum_g Y;  se[n] = sum_g exp(mu+X.beta)
//   K2:     sum_{n,g} [ st(y+r) - lgY[y] + y*lm - (y+r)*log(r+m) + cg ],
//           lm = dc[n]+mu+X.beta, dc = log sy - log se, m = exp(lm)
//   finalize: out = (float)acc
// Fast path (N=1024,G=20000,P=4): 20 gene-chunks x 250 float4 x 64 row-slabs
// = 1280 blocks (exactly 5/CU). Deep batch-issue of Y loads. LDS lgamma
// table. Tolerance: 2% of ~2.3e9 -> fast transcendentals + Stirling safe.
// ---------------------------------------------------------------------------

#define FG4   5000    // float4s per gene row (G/4)
#define FCH4  250     // float4s per chunk (1000 genes)
#define FNCH  20      // gene chunks
#define FNBLK 1280    // FNCH * 64 row-slabs

__device__ __forceinline__ float fast_rcp(float x) {
    return __builtin_amdgcn_rcpf(x);
}

// Accurate lgamma (table build / setup / generic fallback).
__device__ __forceinline__ float lgamma_pos(float x) {
    float lp = 0.0f;
    if (x < 8.0f) {
        float p = x;
        x += 1.0f;
        while (x < 8.0f) { p *= x; x += 1.0f; }
        lp = __logf(p);
    }
    float inv  = fast_rcp(x);
    float inv2 = inv * inv;
    float ser = inv * (0.08333333333f + inv2 * (-0.002777777778f + inv2 * 7.936507937e-4f));
    return (x - 0.5f) * __logf(x) - x + 0.9189385332f + ser - lp;
}

// Hot-loop lgamma for y+r (>= r ~ 1.4 typ): branchless 2-term Stirling.
__device__ __forceinline__ float stirling_lg(float x) {
    float inv  = fast_rcp(x);
    float inv2 = inv * inv;
    float ser  = inv * (0.08333333333f - 0.002777777778f * inv2);
    return (x - 0.5f) * __logf(x) - x + 0.9189385332f + ser;
}

__device__ __forceinline__ float softplus_f(float x) {
    return fmaxf(x, 0.0f) + log1pf(__expf(-fabsf(x)));
}

__device__ __forceinline__ float wave_reduce(float v) {
#pragma unroll
    for (int off = 32; off; off >>= 1) v += __shfl_down(v, off, 64);
    return v;
}

// ---------------------------------------------------------------------------
// K0 setup: priors + per-gene r[g], cg[g].
// ---------------------------------------------------------------------------
__global__ __launch_bounds__(256) void setup_kernel(
        const float* __restrict__ mu, const float* __restrict__ beta,
        const float* __restrict__ phi, double* __restrict__ acc,
        float* __restrict__ rg, float* __restrict__ cgw, int P, int G) {
    int g = blockIdx.x * 256 + threadIdx.x;
    float v = 0.0f;
    if (g < G) {
        const float cn = -1.6120857137646180f;  // -0.5*log(8*pi)
        float m = mu[g];
        v = cn - m * m * 0.125f;
        for (int p = 0; p < P; ++p) {
            float b = beta[(size_t)p * G + g];
            v += cn - b * b * 0.125f;
        }
        float sp = softplus_f(phi[g]);
        v += __logf(sp) - sp;
        float r = 1.0f / sp;
        rg[g]  = r;
        cgw[g] = r * __logf(r) - lgamma_pos(r);
    }
    v = wave_reduce(v);
    __shared__ float red[4];
    int lane = threadIdx.x & 63, wid = threadIdx.x >> 6;
    if (lane == 0) red[wid] = v;
    __syncthreads();
    if (threadIdx.x == 0)
        atomicAdd(acc, (double)((red[0] + red[1]) + (red[2] + red[3])));
}

// ---------------------------------------------------------------------------
// K1 pre: sy/se per row. 1280 blocks, 16 float4 rows in flight.
// ---------------------------------------------------------------------------
__global__ __launch_bounds__(256, 5) void pre_fast(
        const float* __restrict__ X, const float* __restrict__ Y,
        const float* __restrict__ mu, const float* __restrict__ beta,
        float* __restrict__ syw, float* __restrict__ sew) {
    __shared__ float Xs[64];
    __shared__ float syp[4][16], sep[4][16];

    const int tid  = threadIdx.x;
    const int lane = tid & 63, wid = tid >> 6;
    const int c    = blockIdx.x % FNCH;
    const int s    = blockIdx.x / FNCH;
    const int n0   = s * 16;
    const bool active = (tid < FCH4);
    const int gi4  = c * FCH4 + (active ? tid : FCH4 - 1);

    // issue all 16 Y row loads first (deep MLP)
    const float4* __restrict__ Yp = (const float4*)Y + (size_t)n0 * FG4 + gi4;
    float4 ya[16];
#pragma unroll
    for (int j = 0; j < 16; ++j) ya[j] = Yp[(size_t)j * FG4];

    // stage X while loads fly
    if (tid < 64) Xs[tid] = X[(size_t)n0 * 4 + tid];
    const float4* __restrict__ B4 = (const float4*)beta;
    float4 bb[4], mug;
#pragma unroll
    for (int p = 0; p < 4; ++p) bb[p] = B4[(size_t)p * FG4 + gi4];
    mug = ((const float4*)mu)[gi4];
    __syncthreads();

#pragma unroll
    for (int i0 = 0; i0 < 16; i0 += 4) {
        float sy[4], se[4];
#pragma unroll
        for (int j = 0; j < 4; ++j) {
            const int i = i0 + j;
            float4 y = ya[i];
            float4 lu = mug;
#pragma unroll
            for (int p = 0; p < 4; ++p) {
                float xp = Xs[i * 4 + p];
                lu.x = fmaf(xp, bb[p].x, lu.x);
                lu.y = fmaf(xp, bb[p].y, lu.y);
                lu.z = fmaf(xp, bb[p].z, lu.z);
                lu.w = fmaf(xp, bb[p].w, lu.w);
            }
            float e = (__expf(lu.x) + __expf(lu.y)) + (__expf(lu.z) + __expf(lu.w));
            se[j] = active ? e : 0.0f;
            sy[j] = active ? ((y.x + y.y) + (y.z + y.w)) : 0.0f;
        }
#pragma unroll
        for (int off = 32; off; off >>= 1) {
#pragma unroll
            for (int j = 0; j < 4; ++j) {
                sy[j] += __shfl_down(sy[j], off, 64);
                se[j] += __shfl_down(se[j], off, 64);
            }
        }
        if (lane == 0) {
#pragma unroll
            for (int j = 0; j < 4; ++j) {
                syp[wid][i0 + j] = sy[j];
                sep[wid][i0 + j] = se[j];
            }
        }
    }
    __syncthreads();
    if (tid < 16) {
        float a = (syp[0][tid] + syp[1][tid]) + (syp[2][tid] + syp[3][tid]);
        float b = (sep[0][tid] + sep[1][tid]) + (sep[2][tid] + sep[3][tid]);
        atomicAdd(&syw[n0 + tid], a);
        atomicAdd(&sew[n0 + tid], b);
    }
}

// ---------------------------------------------------------------------------
// K2: likelihood. 1280 blocks; batch-8 load issue; LDS lgamma(y+1) table.
// ---------------------------------------------------------------------------
__global__ __launch_bounds__(256, 5) void nb_fast(
        const float* __restrict__ X, const float* __restrict__ Y,
        const float* __restrict__ mu, const float* __restrict__ beta,
        const float* __restrict__ rg, const float* __restrict__ cgw,
        const float* __restrict__ syw, const float* __restrict__ sew,
        double* __restrict__ acc) {
    __shared__ float lgY[512];
    __shared__ float Xs[64];
    __shared__ float dcs[16];
    __shared__ float red[4];

    const int tid  = threadIdx.x;
    const int lane = tid & 63, wid = tid >> 6;
    const int c    = blockIdx.x % FNCH;
    const int s    = blockIdx.x / FNCH;
    const int n0   = s * 16;
    const bool active = (tid < FCH4);
    const int gi4  = c * FCH4 + (active ? tid : FCH4 - 1);

    // batch A: 8 row loads in flight
    const float4* __restrict__ Yp = (const float4*)Y + (size_t)n0 * FG4 + gi4;
    float4 ya[8];
#pragma unroll
    for (int j = 0; j < 8; ++j) ya[j] = Yp[(size_t)j * FG4];

    // stage table/X/dc while loads fly
    for (int i = tid; i < 500; i += 256) lgY[i] = lgamma_pos((float)(i + 1));
    if (tid < 64) Xs[tid] = X[(size_t)n0 * 4 + tid];
    if (tid < 16) dcs[tid] = __logf(syw[n0 + tid]) - __logf(sew[n0 + tid]);

    const float4* __restrict__ B4 = (const float4*)beta;
    float4 bb[4], mug, r4, cg4;
#pragma unroll
    for (int p = 0; p < 4; ++p) bb[p] = B4[(size_t)p * FG4 + gi4];
    mug = ((const float4*)mu)[gi4];
    r4  = ((const float4*)rg)[gi4];
    cg4 = ((const float4*)cgw)[gi4];
    __syncthreads();

    float t0 = 0.0f, t1 = 0.0f, t2 = 0.0f, t3 = 0.0f;
    auto elem = [&](int i, float4 y) {
        float dcn = dcs[i];
        float4 lu = mug;
#pragma unroll
        for (int p = 0; p < 4; ++p) {
            float xp = Xs[i * 4 + p];
            lu.x = fmaf(xp, bb[p].x, lu.x);
            lu.y = fmaf(xp, bb[p].y, lu.y);
            lu.z = fmaf(xp, bb[p].z, lu.z);
            lu.w = fmaf(xp, bb[p].w, lu.w);
        }
        float lm, m, yr;
        lm = dcn + lu.x; m = __expf(lm); yr = y.x + r4.x;
        t0 += stirling_lg(yr) - lgY[__float2int_rz(y.x)]
            + fmaf(y.x, lm, -yr * __logf(r4.x + m)) + cg4.x;
        lm = dcn + lu.y; m = __expf(lm); yr = y.y + r4.y;
        t1 += stirling_lg(yr) - lgY[__float2int_rz(y.y)]
            + fmaf(y.y, lm, -yr * __logf(r4.y + m)) + cg4.y;
        lm = dcn + lu.z; m = __expf(lm); yr = y.z + r4.z;
        t2 += stirling_lg(yr) - lgY[__float2int_rz(y.z)]
            + fmaf(y.z, lm, -yr * __logf(r4.z + m)) + cg4.z;
        lm = dcn + lu.w; m = __expf(lm); yr = y.w + r4.w;
        t3 += stirling_lg(yr) - lgY[__float2int_rz(y.w)]
            + fmaf(y.w, lm, -yr * __logf(r4.w + m)) + cg4.w;
    };

    // issue batch B, then consume A, then consume B
    float4 yb[8];
#pragma unroll
    for (int j = 0; j < 8; ++j) yb[j] = Yp[(size_t)(8 + j) * FG4];
#pragma unroll
    for (int i = 0; i < 8; ++i) elem(i, ya[i]);
#pragma unroll
    for (int i = 0; i < 8; ++i) elem(8 + i, yb[i]);

    float accl = active ? ((t0 + t1) + (t2 + t3)) : 0.0f;
    accl = wave_reduce(accl);
    if (lane == 0) red[wid] = accl;
    __syncthreads();
    if (tid == 0)
        atomicAdd(acc, (double)((red[0] + red[1]) + (red[2] + red[3])));
}

__global__ void finalize_kernel(const double* __restrict__ acc, float* __restrict__ out) {
    out[0] = (float)acc[0];
}

// ---------------------------------------------------------------------------
// Generic fallbacks (correctness only).
// ---------------------------------------------------------------------------
__global__ void row_stats_generic(
        const float* __restrict__ X, const float* __restrict__ Y,
        const float* __restrict__ mu, const float* __restrict__ beta,
        float* __restrict__ syw, float* __restrict__ sew, int N, int P, int G) {
    const int n = blockIdx.x;
    const int tid = threadIdx.x;
    float sy = 0.0f, se = 0.0f;
    for (int g = tid; g < G; g += 256) {
        sy += Y[(size_t)n * G + g];
        float lu = mu[g];
        for (int p = 0; p < P; ++p) lu += X[(size_t)n * P + p] * beta[(size_t)p * G + g];
        se += __expf(lu);
    }
    sy = wave_reduce(sy);
    se = wave_reduce(se);
    __shared__ float r1[4], r2[4];
    int lane = tid & 63, wid = tid >> 6;
    if (lane == 0) { r1[wid] = sy; r2[wid] = se; }
    __syncthreads();
    if (tid == 0) {
        syw[n] = (r1[0] + r1[1]) + (r1[2] + r1[3]);
        sew[n] = (r2[0] + r2[1]) + (r2[2] + r2[3]);
    }
}

__global__ void nb_generic(
        const float* __restrict__ X, const float* __restrict__ Y,
        const float* __restrict__ mu, const float* __restrict__ beta,
        const float* __restrict__ rg, const float* __restrict__ cgw,
        const float* __restrict__ syw, const float* __restrict__ sew,
        double* __restrict__ acc, int N, int P, int G) {
    const int n = blockIdx.x;
    const int tid = threadIdx.x;
    float dcn = __logf(syw[n]) - __logf(sew[n]);
    float accl = 0.0f;
    for (int g = tid; g < G; g += 256) {
        float y = Y[(size_t)n * G + g];
        float lu = mu[g];
        for (int p = 0; p < P; ++p) lu += X[(size_t)n * P + p] * beta[(size_t)p * G + g];
        float lm = dcn + lu;
        float r = rg[g];
        float m = __expf(lm);
        accl += stirling_lg(y + r) - lgamma_pos(y + 1.0f)
                + fmaf(y, lm, -(y + r) * __logf(r + m)) + cgw[g];
    }
    accl = wave_reduce(accl);
    __shared__ float red[4];
    int lane = tid & 63, wid = tid >> 6;
    if (lane == 0) red[wid] = accl;
    __syncthreads();
    if (tid == 0)
        atomicAdd(acc, (double)((red[0] + red[1]) + (red[2] + red[3])));
}

// ---------------------------------------------------------------------------
extern "C" void kernel_launch(void* const* d_in, const int* in_sizes, int n_in,
                              void* d_out, int out_size, void* d_ws, size_t ws_size,
                              hipStream_t stream) {
    const float* X    = (const float*)d_in[0];
    const float* Y    = (const float*)d_in[1];
    const float* mu   = (const float*)d_in[2];
    const float* beta = (const float*)d_in[3];
    const float* phi  = (const float*)d_in[4];
    float* out = (float*)d_out;

    const int G = in_sizes[2];
    const int N = in_sizes[1] / G;
    const int P = in_sizes[0] / N;

    // ws layout: acc@0 | syw@256 [N] | sew@4608 [N] | rg@8960 [G] | cg@8960+4G [G]
    char* ws = (char*)d_ws;
    double* acc = (double*)ws;
    float*  syw = (float*)(ws + 256);
    float*  sew = (float*)(ws + 4608);
    float*  rgw = (float*)(ws + 8960);
    float*  cgw = (float*)(ws + 8960 + (size_t)4 * G);

    hipMemsetAsync(d_ws, 0, 8960, stream);   // acc + syw + sew

    const bool fast_ok = (N == 1024 && G == 20000 && P == 4);
    int gblocks = (G + 255) / 256;

    if (fast_ok) {
        pre_fast<<<FNBLK, 256, 0, stream>>>(X, Y, mu, beta, syw, sew);
        setup_kernel<<<gblocks, 256, 0, stream>>>(mu, beta, phi, acc, rgw, cgw, P, G);
        nb_fast<<<FNBLK, 256, 0, stream>>>(X, Y, mu, beta, rgw, cgw, syw, sew, acc);
    } else {
        setup_kernel<<<gblocks, 256, 0, stream>>>(mu, beta, phi, acc, rgw, cgw, P, G);
        row_stats_generic<<<N, 256, 0, stream>>>(X, Y, mu, beta, syw, sew, N, P, G);
        nb_generic<<<N, 256, 0, stream>>>(X, Y, mu, beta, rgw, cgw, syw, sew,
                                          acc, N, P, G);
    }
    finalize_kernel<<<1, 1, 0, stream>>>(acc, out);
}

// Round 12
// 166.506 us; speedup vs baseline: 1.1403x; 1.1403x over previous
//
#include <hip/hip_runtime.h>
#include <math.h>

// ---------------------------------------------------------------------------
// NB regression log-posterior, two-pass. EXACT R8 configuration (measured
// best: 167.3 us R8, 168.5 us R10). launch_bounds(256,4); 1280 one-item
// blocks; deep batch-issue of Y loads; LDS lgamma(y+1) table in nb.
//
// Session findings (R1-R11): each pass over Y costs ~45-48 us invariant to
// bytes (0.5x-8x), VGPR (12-104), blocks/CU (1-5), prefetch depth (0-16),
// and decomposition shape. (256,5) regressed (forced reg cap); coop fusion
// regressed (serialization); kernel merging regressed (serialized tail);
// ushort packing regressed (write stream cost). Total = ~75 us harness
// poison-fill floor + 2 passes + ~5 us small dispatches ~= 167 us.
//   setup:  priors + per-gene r, cg = r*log r - lgamma(r)
//   pre:    sy[n] = sum_g Y;  se[n] = sum_g exp(mu+X.beta)
//   nb:     sum_{n,g} [ st(y+r) - lgY[y] + y*lm - (y+r)*log(r+m) + cg ],
//           lm = dc[n]+mu+X.beta, dc = log sy - log se, m = exp(lm)
//   finalize: out = (float)acc
// Tolerance: 2% of ~2.3e9 -> fast transcendentals + 2-term Stirling safe.
// ---------------------------------------------------------------------------

#define FG4   5000    // float4s per gene row (G/4)
#define FCH4  250     // float4s per chunk (1000 genes)
#define FNCH  20      // gene chunks
#define FNBLK 1280    // FNCH * 64 row-slabs

__device__ __forceinline__ float fast_rcp(float x) {
    return __builtin_amdgcn_rcpf(x);
}

// Accurate lgamma (table build / setup / generic fallback).
__device__ __forceinline__ float lgamma_pos(float x) {
    float lp = 0.0f;
    if (x < 8.0f) {
        float p = x;
        x += 1.0f;
        while (x < 8.0f) { p *= x; x += 1.0f; }
        lp = __logf(p);
    }
    float inv  = fast_rcp(x);
    float inv2 = inv * inv;
    float ser = inv * (0.08333333333f + inv2 * (-0.002777777778f + inv2 * 7.936507937e-4f));
    return (x - 0.5f) * __logf(x) - x + 0.9189385332f + ser - lp;
}

// Hot-loop lgamma for y+r (>= r ~ 1.4 typ): branchless 2-term Stirling.
__device__ __forceinline__ float stirling_lg(float x) {
    float inv  = fast_rcp(x);
    float inv2 = inv * inv;
    float ser  = inv * (0.08333333333f - 0.002777777778f * inv2);
    return (x - 0.5f) * __logf(x) - x + 0.9189385332f + ser;
}

__device__ __forceinline__ float softplus_f(float x) {
    return fmaxf(x, 0.0f) + log1pf(__expf(-fabsf(x)));
}

__device__ __forceinline__ float wave_reduce(float v) {
#pragma unroll
    for (int off = 32; off; off >>= 1) v += __shfl_down(v, off, 64);
    return v;
}

// ---------------------------------------------------------------------------
// K0 setup: priors + per-gene r[g], cg[g].
// ---------------------------------------------------------------------------
__global__ __launch_bounds__(256) void setup_kernel(
        const float* __restrict__ mu, const float* __restrict__ beta,
        const float* __restrict__ phi, double* __restrict__ acc,
        float* __restrict__ rg, float* __restrict__ cgw, int P, int G) {
    int g = blockIdx.x * 256 + threadIdx.x;
    float v = 0.0f;
    if (g < G) {
        const float cn = -1.6120857137646180f;  // -0.5*log(8*pi)
        float m = mu[g];
        v = cn - m * m * 0.125f;
        for (int p = 0; p < P; ++p) {
            float b = beta[(size_t)p * G + g];
            v += cn - b * b * 0.125f;
        }
        float sp = softplus_f(phi[g]);
        v += __logf(sp) - sp;
        float r = 1.0f / sp;
        rg[g]  = r;
        cgw[g] = r * __logf(r) - lgamma_pos(r);
    }
    v = wave_reduce(v);
    __shared__ float red[4];
    int lane = threadIdx.x & 63, wid = threadIdx.x >> 6;
    if (lane == 0) red[wid] = v;
    __syncthreads();
    if (threadIdx.x == 0)
        atomicAdd(acc, (double)((red[0] + red[1]) + (red[2] + red[3])));
}

// ---------------------------------------------------------------------------
// K1 pre: sy/se per row. 1280 blocks, 16 float4 rows in flight.
// ---------------------------------------------------------------------------
__global__ __launch_bounds__(256, 4) void pre_fast(
        const float* __restrict__ X, const float* __restrict__ Y,
        const float* __restrict__ mu, const float* __restrict__ beta,
        float* __restrict__ syw, float* __restrict__ sew) {
    __shared__ float Xs[64];
    __shared__ float syp[4][16], sep[4][16];

    const int tid  = threadIdx.x;
    const int lane = tid & 63, wid = tid >> 6;
    const int c    = blockIdx.x % FNCH;
    const int s    = blockIdx.x / FNCH;
    const int n0   = s * 16;
    const bool active = (tid < FCH4);
    const int gi4  = c * FCH4 + (active ? tid : FCH4 - 1);

    // issue all 16 Y row loads first (deep MLP)
    const float4* __restrict__ Yp = (const float4*)Y + (size_t)n0 * FG4 + gi4;
    float4 ya[16];
#pragma unroll
    for (int j = 0; j < 16; ++j) ya[j] = Yp[(size_t)j * FG4];

    // stage X while loads fly
    if (tid < 64) Xs[tid] = X[(size_t)n0 * 4 + tid];
    const float4* __restrict__ B4 = (const float4*)beta;
    float4 bb[4], mug;
#pragma unroll
    for (int p = 0; p < 4; ++p) bb[p] = B4[(size_t)p * FG4 + gi4];
    mug = ((const float4*)mu)[gi4];
    __syncthreads();

#pragma unroll
    for (int i0 = 0; i0 < 16; i0 += 4) {
        float sy[4], se[4];
#pragma unroll
        for (int j = 0; j < 4; ++j) {
            const int i = i0 + j;
            float4 y = ya[i];
            float4 lu = mug;
#pragma unroll
            for (int p = 0; p < 4; ++p) {
                float xp = Xs[i * 4 + p];
                lu.x = fmaf(xp, bb[p].x, lu.x);
                lu.y = fmaf(xp, bb[p].y, lu.y);
                lu.z = fmaf(xp, bb[p].z, lu.z);
                lu.w = fmaf(xp, bb[p].w, lu.w);
            }
            float e = (__expf(lu.x) + __expf(lu.y)) + (__expf(lu.z) + __expf(lu.w));
            se[j] = active ? e : 0.0f;
            sy[j] = active ? ((y.x + y.y) + (y.z + y.w)) : 0.0f;
        }
#pragma unroll
        for (int off = 32; off; off >>= 1) {
#pragma unroll
            for (int j = 0; j < 4; ++j) {
                sy[j] += __shfl_down(sy[j], off, 64);
                se[j] += __shfl_down(se[j], off, 64);
            }
        }
        if (lane == 0) {
#pragma unroll
            for (int j = 0; j < 4; ++j) {
                syp[wid][i0 + j] = sy[j];
                sep[wid][i0 + j] = se[j];
            }
        }
    }
    __syncthreads();
    if (tid < 16) {
        float a = (syp[0][tid] + syp[1][tid]) + (syp[2][tid] + syp[3][tid]);
        float b = (sep[0][tid] + sep[1][tid]) + (sep[2][tid] + sep[3][tid]);
        atomicAdd(&syw[n0 + tid], a);
        atomicAdd(&sew[n0 + tid], b);
    }
}

// ---------------------------------------------------------------------------
// K2: likelihood. 1280 blocks; batch-8 load issue; LDS lgamma(y+1) table.
// ---------------------------------------------------------------------------
__global__ __launch_bounds__(256, 4) void nb_fast(
        const float* __restrict__ X, const float* __restrict__ Y,
        const float* __restrict__ mu, const float* __restrict__ beta,
        const float* __restrict__ rg, const float* __restrict__ cgw,
        const float* __restrict__ syw, const float* __restrict__ sew,
        double* __restrict__ acc) {
    __shared__ float lgY[512];
    __shared__ float Xs[64];
    __shared__ float dcs[16];
    __shared__ float red[4];

    const int tid  = threadIdx.x;
    const int lane = tid & 63, wid = tid >> 6;
    const int c    = blockIdx.x % FNCH;
    const int s    = blockIdx.x / FNCH;
    const int n0   = s * 16;
    const bool active = (tid < FCH4);
    const int gi4  = c * FCH4 + (active ? tid : FCH4 - 1);

    // batch A: 8 row loads in flight
    const float4* __restrict__ Yp = (const float4*)Y + (size_t)n0 * FG4 + gi4;
    float4 ya[8];
#pragma unroll
    for (int j = 0; j < 8; ++j) ya[j] = Yp[(size_t)j * FG4];

    // stage table/X/dc while loads fly
    for (int i = tid; i < 500; i += 256) lgY[i] = lgamma_pos((float)(i + 1));
    if (tid < 64) Xs[tid] = X[(size_t)n0 * 4 + tid];
    if (tid < 16) dcs[tid] = __logf(syw[n0 + tid]) - __logf(sew[n0 + tid]);

    const float4* __restrict__ B4 = (const float4*)beta;
    float4 bb[4], mug, r4, cg4;
#pragma unroll
    for (int p = 0; p < 4; ++p) bb[p] = B4[(size_t)p * FG4 + gi4];
    mug = ((const float4*)mu)[gi4];
    r4  = ((const float4*)rg)[gi4];
    cg4 = ((const float4*)cgw)[gi4];
    __syncthreads();

    float t0 = 0.0f, t1 = 0.0f, t2 = 0.0f, t3 = 0.0f;
    auto elem = [&](int i, float4 y) {
        float dcn = dcs[i];
        float4 lu = mug;
#pragma unroll
        for (int p = 0; p < 4; ++p) {
            float xp = Xs[i * 4 + p];
            lu.x = fmaf(xp, bb[p].x, lu.x);
            lu.y = fmaf(xp, bb[p].y, lu.y);
            lu.z = fmaf(xp, bb[p].z, lu.z);
            lu.w = fmaf(xp, bb[p].w, lu.w);
        }
        float lm, m, yr;
        lm = dcn + lu.x; m = __expf(lm); yr = y.x + r4.x;
        t0 += stirling_lg(yr) - lgY[__float2int_rz(y.x)]
            + fmaf(y.x, lm, -yr * __logf(r4.x + m)) + cg4.x;
        lm = dcn + lu.y; m = __expf(lm); yr = y.y + r4.y;
        t1 += stirling_lg(yr) - lgY[__float2int_rz(y.y)]
            + fmaf(y.y, lm, -yr * __logf(r4.y + m)) + cg4.y;
        lm = dcn + lu.z; m = __expf(lm); yr = y.z + r4.z;
        t2 += stirling_lg(yr) - lgY[__float2int_rz(y.z)]
            + fmaf(y.z, lm, -yr * __logf(r4.z + m)) + cg4.z;
        lm = dcn + lu.w; m = __expf(lm); yr = y.w + r4.w;
        t3 += stirling_lg(yr) - lgY[__float2int_rz(y.w)]
            + fmaf(y.w, lm, -yr * __logf(r4.w + m)) + cg4.w;
    };

    // issue batch B, then consume A, then consume B
    float4 yb[8];
#pragma unroll
    for (int j = 0; j < 8; ++j) yb[j] = Yp[(size_t)(8 + j) * FG4];
#pragma unroll
    for (int i = 0; i < 8; ++i) elem(i, ya[i]);
#pragma unroll
    for (int i = 0; i < 8; ++i) elem(8 + i, yb[i]);

    float accl = active ? ((t0 + t1) + (t2 + t3)) : 0.0f;
    accl = wave_reduce(accl);
    if (lane == 0) red[wid] = accl;
    __syncthreads();
    if (tid == 0)
        atomicAdd(acc, (double)((red[0] + red[1]) + (red[2] + red[3])));
}

__global__ void finalize_kernel(const double* __restrict__ acc, float* __restrict__ out) {
    out[0] = (float)acc[0];
}

// ---------------------------------------------------------------------------
// Generic fallbacks (correctness only).
// ---------------------------------------------------------------------------
__global__ void row_stats_generic(
        const float* __restrict__ X, const float* __restrict__ Y,
        const float* __restrict__ mu, const float* __restrict__ beta,
        float* __restrict__ syw, float* __restrict__ sew, int N, int P, int G) {
    const int n = blockIdx.x;
    const int tid = threadIdx.x;
    float sy = 0.0f, se = 0.0f;
    for (int g = tid; g < G; g += 256) {
        sy += Y[(size_t)n * G + g];
        float lu = mu[g];
        for (int p = 0; p < P; ++p) lu += X[(size_t)n * P + p] * beta[(size_t)p * G + g];
        se += __expf(lu);
    }
    sy = wave_reduce(sy);
    se = wave_reduce(se);
    __shared__ float r1[4], r2[4];
    int lane = tid & 63, wid = tid >> 6;
    if (lane == 0) { r1[wid] = sy; r2[wid] = se; }
    __syncthreads();
    if (tid == 0) {
        syw[n] = (r1[0] + r1[1]) + (r1[2] + r1[3]);
        sew[n] = (r2[0] + r2[1]) + (r2[2] + r2[3]);
    }
}

__global__ void nb_generic(
        const float* __restrict__ X, const float* __restrict__ Y,
        const float* __restrict__ mu, const float* __restrict__ beta,
        const float* __restrict__ rg, const float* __restrict__ cgw,
        const float* __restrict__ syw, const float* __restrict__ sew,
        double* __restrict__ acc, int N, int P, int G) {
    const int n = blockIdx.x;
    const int tid = threadIdx.x;
    float dcn = __logf(syw[n]) - __logf(sew[n]);
    float accl = 0.0f;
    for (int g = tid; g < G; g += 256) {
        float y = Y[(size_t)n * G + g];
        float lu = mu[g];
        for (int p = 0; p < P; ++p) lu += X[(size_t)n * P + p] * beta[(size_t)p * G + g];
        float lm = dcn + lu;
        float r = rg[g];
        float m = __expf(lm);
        accl += stirling_lg(y + r) - lgamma_pos(y + 1.0f)
                + fmaf(y, lm, -(y + r) * __logf(r + m)) + cgw[g];
    }
    accl = wave_reduce(accl);
    __shared__ float red[4];
    int lane = tid & 63, wid = tid >> 6;
    if (lane == 0) red[wid] = accl;
    __syncthreads();
    if (tid == 0)
        atomicAdd(acc, (double)((red[0] + red[1]) + (red[2] + red[3])));
}

// ---------------------------------------------------------------------------
extern "C" void kernel_launch(void* const* d_in, const int* in_sizes, int n_in,
                              void* d_out, int out_size, void* d_ws, size_t ws_size,
                              hipStream_t stream) {
    const float* X    = (const float*)d_in[0];
    const float* Y    = (const float*)d_in[1];
    const float* mu   = (const float*)d_in[2];
    const float* beta = (const float*)d_in[3];
    const float* phi  = (const float*)d_in[4];
    float* out = (float*)d_out;

    const int G = in_sizes[2];
    const int N = in_sizes[1] / G;
    const int P = in_sizes[0] / N;

    // ws layout: acc@0 | syw@256 [N] | sew@4608 [N] | rg@8960 [G] | cg@8960+4G [G]
    char* ws = (char*)d_ws;
    double* acc = (double*)ws;
    float*  syw = (float*)(ws + 256);
    float*  sew = (float*)(ws + 4608);
    float*  rgw = (float*)(ws + 8960);
    float*  cgw = (float*)(ws + 8960 + (size_t)4 * G);

    hipMemsetAsync(d_ws, 0, 8960, stream);   // acc + syw + sew

    const bool fast_ok = (N == 1024 && G == 20000 && P == 4);
    int gblocks = (G + 255) / 256;

    if (fast_ok) {
        pre_fast<<<FNBLK, 256, 0, stream>>>(X, Y, mu, beta, syw, sew);
        setup_kernel<<<gblocks, 256, 0, stream>>>(mu, beta, phi, acc, rgw, cgw, P, G);
        nb_fast<<<FNBLK, 256, 0, stream>>>(X, Y, mu, beta, rgw, cgw, syw, sew, acc);
    } else {
        setup_kernel<<<gblocks, 256, 0, stream>>>(mu, beta, phi, acc, rgw, cgw, P, G);
        row_stats_generic<<<N, 256, 0, stream>>>(X, Y, mu, beta, syw, sew, N, P, G);
        nb_generic<<<N, 256, 0, stream>>>(X, Y, mu, beta, rgw, cgw, syw, sew,
                                          acc, N, P, G);
    }
    finalize_kernel<<<1, 1, 0, stream>>>(acc, out);
}